// Round 8
// baseline (257.694 us; speedup 1.0000x reference)
//
#include <hip/hip_runtime.h>
#include <math.h>

#define BB 256
#define LL 500
#define EE 300
#define NROWS (BB * LL)      // 128000
#define NJ 18                // 3 (aw3) + 1 (cw3) + 5 (aw5) + 1 (cw5) + 7 (aw7) + 1 (cw7)
#define NC 75                // float4 chunks per row
#define TOUT 122             // outputs per block
#define NTILE 5              // ceil(500/122)
#define DROWS 128            // dot rows per block = 4 waves * 32 rows

// ---------------------------------------------------------------------------
// Fully fused, weights-in-LDS. R8 reshape: 8 lanes/row x 4 rows/group x
// 8 groups = 32 rows/wave (was 16). Halves per-row cross-lane reduction cost
// (3-step butterfly over 8 lanes, masks 1/2 lower to quad-perm DPP) and
// doubles per-wave independent FMA work (9-10 k-steps x 288 FMA instrs) so
// each 4-load x convoy is covered by ~576 cycles of compute.
// Block = 4 waves -> 128 dot-rows -> 122 outputs. No workspace.
// ---------------------------------------------------------------------------
__global__ __launch_bounds__(256) void fused_kernel(
    const float* __restrict__ x,
    const float* __restrict__ aw3, const float* __restrict__ ab3,
    const float* __restrict__ cw3, const float* __restrict__ cb3,
    const float* __restrict__ aw5, const float* __restrict__ ab5,
    const float* __restrict__ cw5, const float* __restrict__ cb5,
    const float* __restrict__ aw7, const float* __restrict__ ab7,
    const float* __restrict__ cw7, const float* __restrict__ cb7,
    float* __restrict__ out)
{
    __shared__ float4 wlds[NJ * NC];         // 1350 float4 = 21.6 KB
    __shared__ float dlds[DROWS][NJ + 1];    // stride 19, conflict-free (9.7 KB)

    const int tid = threadIdx.x;

    // ---- cooperative weight staging: 6 contiguous segments ----
    {
        const float4* s3a = (const float4*)aw3;   // 225
        const float4* s3c = (const float4*)cw3;   // 75
        const float4* s5a = (const float4*)aw5;   // 375
        const float4* s5c = (const float4*)cw5;   // 75
        const float4* s7a = (const float4*)aw7;   // 525
        const float4* s7c = (const float4*)cw7;   // 75
        for (int i = tid; i < 225; i += 256) wlds[i]        = s3a[i];
        for (int i = tid; i < 75;  i += 256) wlds[225 + i]  = s3c[i];
        for (int i = tid; i < 375; i += 256) wlds[300 + i]  = s5a[i];
        for (int i = tid; i < 75;  i += 256) wlds[675 + i]  = s5c[i];
        for (int i = tid; i < 525; i += 256) wlds[750 + i]  = s7a[i];
        for (int i = tid; i < 75;  i += 256) wlds[1275 + i] = s7c[i];
    }

    const int b    = blockIdx.x / NTILE;
    const int t    = blockIdx.x % NTILE;
    const int l0   = t * TOUT - 3;           // global l of local dot-row 0
    const int wave = tid >> 6;               // 0..3
    const int lane = tid & 63;
    const int g    = lane >> 3;              // 0..7
    const int j    = lane & 7;               // 0..7
    const int lr   = wave * 32 + g * 4;      // local dot-row base (0..124)

    // clamped x row pointers + validity (invalid rows -> zero dots = zero pad)
    bool valid[4];
    const float4* xr[4];
#pragma unroll
    for (int rr = 0; rr < 4; ++rr) {
        const int l = l0 + lr + rr;
        valid[rr] = (l >= 0) && (l < LL);
        const int lc = l < 0 ? 0 : (l >= LL ? LL - 1 : l);
        xr[rr] = (const float4*)(x + ((size_t)b * LL + lc) * EE);
    }

    // first x chunk overlaps weight staging
    float4 xc[4];
#pragma unroll
    for (int rr = 0; rr < 4; ++rr) xc[rr] = xr[rr][j];

    __syncthreads();   // wlds visible

    float acc[NJ][4];
#pragma unroll
    for (int d = 0; d < NJ; ++d)
#pragma unroll
        for (int rr = 0; rr < 4; ++rr) acc[d][rr] = 0.0f;

#define COMPUTE(c)                                                                  \
    {                                                                               \
        _Pragma("unroll")                                                           \
        for (int d = 0; d < NJ; ++d) {                                              \
            const float4 w = wlds[d * NC + (c)];                                    \
            acc[d][0] = fmaf(xc[0].w, w.w, fmaf(xc[0].z, w.z, fmaf(xc[0].y, w.y, fmaf(xc[0].x, w.x, acc[d][0])))); \
            acc[d][1] = fmaf(xc[1].w, w.w, fmaf(xc[1].z, w.z, fmaf(xc[1].y, w.y, fmaf(xc[1].x, w.x, acc[d][1])))); \
            acc[d][2] = fmaf(xc[2].w, w.w, fmaf(xc[2].z, w.z, fmaf(xc[2].y, w.y, fmaf(xc[2].x, w.x, acc[d][2])))); \
            acc[d][3] = fmaf(xc[3].w, w.w, fmaf(xc[3].z, w.z, fmaf(xc[3].y, w.y, fmaf(xc[3].x, w.x, acc[d][3])))); \
        }                                                                           \
    }

    // chunk loop: lane j covers chunks j, j+8, ..., j+64 (9 steps) and,
    // for j<3, the tail chunk j+72 (chunks 72..74).
    for (int k = 0; k < 9; ++k) {
        const int cn = (k == 8) ? ((j < 3) ? (j + 72) : 74) : (j + 8 * (k + 1));
        float4 xn[4];
#pragma unroll
        for (int rr = 0; rr < 4; ++rr) xn[rr] = xr[rr][cn];   // prefetch next
        COMPUTE(j + 8 * k)                                    // compute current
#pragma unroll
        for (int rr = 0; rr < 4; ++rr) xc[rr] = xn[rr];
    }
    if (j < 3) {
        COMPUTE(j + 72)
    }
#undef COMPUTE

    // 3-step butterfly across the 8-lane group (masks 1,2 -> quad-perm DPP)
#pragma unroll
    for (int d = 0; d < NJ; ++d)
#pragma unroll
        for (int rr = 0; rr < 4; ++rr) {
            float v = acc[d][rr];
            v += __shfl_xor(v, 1);
            v += __shfl_xor(v, 2);
            v += __shfl_xor(v, 4);
            acc[d][rr] = v;
        }

    // lane j == rr stores row lr+rr into LDS (zeroed if out-of-range).
    // Active lanes for fixed (rr,d): one per 8-group; dlds row stride 19
    // floats -> group stride 76 floats -> banks g*12 mod 32, all distinct.
#pragma unroll
    for (int rr = 0; rr < 4; ++rr) {
        if (j == rr) {
            const float vf = valid[rr] ? 1.0f : 0.0f;
#pragma unroll
            for (int d = 0; d < NJ; ++d) dlds[lr + rr][d] = acc[d][rr] * vf;
        }
    }

    __syncthreads();

    // epilogue: thread tid < TOUT handles output l = t*TOUT + tid (all 3 branches)
    if (tid < TOUT) {
        const int lo = t * TOUT + tid;
        if (lo < LL) {
            const int c = tid + 3;   // local dot-row of the center

            float pre3 = 0.0f, pre5 = 0.0f, pre7 = 0.0f;
#pragma unroll
            for (int tp = 0; tp < 3; ++tp) pre3 += dlds[c + tp - 1][tp];
#pragma unroll
            for (int tp = 0; tp < 5; ++tp) pre5 += dlds[c + tp - 2][4 + tp];
#pragma unroll
            for (int tp = 0; tp < 7; ++tp) pre7 += dlds[c + tp - 3][10 + tp];

            const float c3v = dlds[c][3];
            const float c5v = dlds[c][9];
            const float c7v = dlds[c][17];

            const float s3 = 1.0f / (1.0f + expf(-(pre3 + ab3[0])));
            const float s5 = 1.0f / (1.0f + expf(-(pre5 + ab5[0])));
            const float s7 = 1.0f / (1.0f + expf(-(pre7 + ab7[0])));

            const int r = b * LL + lo;
            out[r]             = tanhf(s3 * c3v + cb3[0]);
            out[NROWS + r]     = tanhf(s5 * c5v + cb5[0]);
            out[2 * NROWS + r] = tanhf(s7 * c7v + cb7[0]);
        }
    }
}

extern "C" void kernel_launch(void* const* d_in, const int* in_sizes, int n_in,
                              void* d_out, int out_size, void* d_ws, size_t ws_size,
                              hipStream_t stream) {
    const float* x   = (const float*)d_in[0];
    const float* aw3 = (const float*)d_in[1];
    const float* ab3 = (const float*)d_in[2];
    const float* cw3 = (const float*)d_in[3];
    const float* cb3 = (const float*)d_in[4];
    const float* aw5 = (const float*)d_in[5];
    const float* ab5 = (const float*)d_in[6];
    const float* cw5 = (const float*)d_in[7];
    const float* cb5 = (const float*)d_in[8];
    const float* aw7 = (const float*)d_in[9];
    const float* ab7 = (const float*)d_in[10];
    const float* cw7 = (const float*)d_in[11];
    const float* cb7 = (const float*)d_in[12];

    float* out = (float*)d_out;  // [out3 | out5 | out7]

    // 256 batches x 5 l-tiles, one dispatch, no workspace
    fused_kernel<<<BB * NTILE, 256, 0, stream>>>(
        x, aw3, ab3, cw3, cb3, aw5, ab5, cw5, cb5, aw7, ab7, cw7, cb7, out);
}